// Round 6
// baseline (389.569 us; speedup 1.0000x reference)
//
#include <hip/hip_runtime.h>

// ---------------------------------------------------------------------------
// RefineIUGraphLayer: D=256, H=16, HD=16, N=16384, B=64, S=128, M=8192
// Identity: p1-normalize needs |.| only in the DENOMINATOR.
//   out = user + diag(c) · U @ (G Wᵀ) + b,  G = SᵀS,  c_i = 1/(max(r_i,eps)·M)
//   r_i = Σ_j |u_i · s_j|   (the only O(N·M·D) kernel)
// Pipeline (8 launches):
//   1) cvt_all: user/seq_feat/in_proj_w/out_proj_w -> bf16
//   2) qkv  = seq_feat @ in_proj_wᵀ + b        (bf16 MFMA gemm)
//   3) attn = MHA(qkv)                         (reg-cached scores, 2 j-halves)
//   4) seq  = attn @ out_proj_wᵀ + b           (gemm, writes seq + seqᵀ)
//   5) r    = rowabs(U @ seqᵀ)                 (hot; j-split x4, 2 blocks/CU)
//   6) G    = seqᵀ seq (split-K partials)
//   7) Hᵀ   = (ΣGpart) @ trans_wᵀ  (bf16, transposed)
//   8) out  = user + diag(c)·(U@H) + trans_b   (c computed in-block)
// ---------------------------------------------------------------------------

typedef __bf16 bf16_t;
typedef __bf16 bf16x8 __attribute__((ext_vector_type(8)));
typedef __bf16 bf16x4 __attribute__((ext_vector_type(4)));
typedef float  f32x4  __attribute__((ext_vector_type(4)));
typedef unsigned int u32x4 __attribute__((ext_vector_type(4)));

#define MFMA16(a, b, c) __builtin_amdgcn_mfma_f32_16x16x32_bf16((a), (b), (c), 0, 0, 0)

#define AS1 __attribute__((address_space(1)))
#define AS3 __attribute__((address_space(3)))
#define GLOAD_LDS16(g, l) \
    __builtin_amdgcn_global_load_lds((const AS1 unsigned int*)(const void*)(g), \
                                     (AS3 unsigned int*)(void*)(l), 16, 0, 0)

// 3-bit chunk XOR swizzle (involution; same on write & read).
__device__ __forceinline__ int swz256(int row, int k) { return row * 256 + (k ^ ((row & 7) << 3)); }

// ------------------ fused f32 -> bf16 convert (all operands) ---------------
__global__ void k_cvt_all(const float* __restrict__ u, const float* __restrict__ x,
                          const float* __restrict__ w1, const float* __restrict__ w2,
                          bf16_t* __restrict__ ub, bf16_t* __restrict__ xb,
                          bf16_t* __restrict__ w1b, bf16_t* __restrict__ w2b) {
    const int NU = 16384 * 256 / 4, NX = 8192 * 256 / 4;
    const int NW1 = 768 * 256 / 4, NW2 = 256 * 256 / 4;
    const int total = NU + NX + NW1 + NW2;
    int i  = blockIdx.x * blockDim.x + threadIdx.x;
    int st = gridDim.x * blockDim.x;
    for (; i < total; i += st) {
        const float* s; bf16_t* d; int k;
        if (i < NU)                { s = u;  d = ub;  k = i; }
        else if (i < NU + NX)      { s = x;  d = xb;  k = i - NU; }
        else if (i < NU + NX + NW1){ s = w1; d = w1b; k = i - NU - NX; }
        else                       { s = w2; d = w2b; k = i - NU - NX - NW1; }
        float4 v = ((const float4*)s)[k];
        bf16x4 o = { (bf16_t)v.x, (bf16_t)v.y, (bf16_t)v.z, (bf16_t)v.w };
        ((bf16x4*)d)[k] = o;
    }
}

// --------------- generic C = A @ Bᵀ + bias, bf16 out -----------------------
__global__ __launch_bounds__(256, 1)
void k_gemm_bt(const bf16_t* __restrict__ A, const bf16_t* __restrict__ B,
               const float* __restrict__ bias, bf16_t* __restrict__ Cb, int N) {
    __shared__ bf16_t Al[64 * 256];
    __shared__ bf16_t Bl[64 * 256];
    const int tid  = threadIdx.x;
    const int lane = tid & 63;
    const int w    = tid >> 6;
    const int l15  = lane & 15;
    const int l4   = lane >> 4;
    const int rb = blockIdx.y * 64, cb = blockIdx.x * 64;

    {
        const u32x4* sa = (const u32x4*)(A + (size_t)rb * 256);
        const u32x4* sb = (const u32x4*)(B + (size_t)cb * 256);
        u32x4* da = (u32x4*)Al;
        u32x4* db = (u32x4*)Bl;
#pragma unroll
        for (int i = 0; i < 8; ++i) {
            int ch  = i * 256 + tid;
            int row = ch >> 5, cp = ch & 31;
            int sch = (ch & ~31) | (cp ^ (row & 7));
            da[sch] = sa[ch];
            db[sch] = sb[ch];
        }
    }
    __syncthreads();

    f32x4 acc[4];
#pragma unroll
    for (int n = 0; n < 4; ++n) acc[n] = (f32x4){0.f, 0.f, 0.f, 0.f};
#pragma unroll
    for (int t = 0; t < 8; ++t) {
        int k = t * 32 + l4 * 8;
        bf16x8 af = *(const bf16x8*)(Al + swz256(16 * w + l15, k));
#pragma unroll
        for (int n = 0; n < 4; ++n) {
            bf16x8 bfr = *(const bf16x8*)(Bl + swz256(16 * n + l15, k));
            acc[n] = MFMA16(af, bfr, acc[n]);
        }
    }
#pragma unroll
    for (int n = 0; n < 4; ++n) {
        int col = cb + 16 * n + l15;
        float bv = bias ? bias[col] : 0.f;
#pragma unroll
        for (int r = 0; r < 4; ++r) {
            int row = rb + 16 * w + l4 * 4 + r;
            Cb[(size_t)row * N + col] = (bf16_t)(acc[n][r] + bv);
        }
    }
}

// -------- seq gemm: C = A @ Bᵀ + bias; writes C (bf16) AND Cᵀ (bf16) -------
__global__ __launch_bounds__(256, 1)
void k_gemm_seqT(const bf16_t* __restrict__ A, const bf16_t* __restrict__ B,
                 const float* __restrict__ bias, bf16_t* __restrict__ Cb,
                 bf16_t* __restrict__ CTb) {
    __shared__ bf16_t Al[64 * 256];
    __shared__ bf16_t Bl[64 * 256];
    __shared__ float  Tt[64][65];
    const int tid  = threadIdx.x;
    const int lane = tid & 63;
    const int w    = tid >> 6;
    const int l15  = lane & 15;
    const int l4   = lane >> 4;
    const int rb = blockIdx.y * 64, cb = blockIdx.x * 64;

    {
        const u32x4* sa = (const u32x4*)(A + (size_t)rb * 256);
        const u32x4* sb = (const u32x4*)(B + (size_t)cb * 256);
        u32x4* da = (u32x4*)Al;
        u32x4* db = (u32x4*)Bl;
#pragma unroll
        for (int i = 0; i < 8; ++i) {
            int ch  = i * 256 + tid;
            int row = ch >> 5, cp = ch & 31;
            int sch = (ch & ~31) | (cp ^ (row & 7));
            da[sch] = sa[ch];
            db[sch] = sb[ch];
        }
    }
    __syncthreads();

    f32x4 acc[4];
#pragma unroll
    for (int n = 0; n < 4; ++n) acc[n] = (f32x4){0.f, 0.f, 0.f, 0.f};
#pragma unroll
    for (int t = 0; t < 8; ++t) {
        int k = t * 32 + l4 * 8;
        bf16x8 af = *(const bf16x8*)(Al + swz256(16 * w + l15, k));
#pragma unroll
        for (int n = 0; n < 4; ++n) {
            bf16x8 bfr = *(const bf16x8*)(Bl + swz256(16 * n + l15, k));
            acc[n] = MFMA16(af, bfr, acc[n]);
        }
    }
#pragma unroll
    for (int n = 0; n < 4; ++n) {
        int col = cb + 16 * n + l15;
        float bv = bias[col];
#pragma unroll
        for (int r = 0; r < 4; ++r) {
            int row = rb + 16 * w + l4 * 4 + r;
            float v = acc[n][r] + bv;
            Cb[(size_t)row * 256 + col] = (bf16_t)v;
            Tt[16 * n + l15][16 * w + l4 * 4 + r] = v;
        }
    }
    __syncthreads();
#pragma unroll
    for (int i = 0; i < 16; ++i) {
        int e = i * 256 + tid;
        int lc = e >> 6, lr = e & 63;
        CTb[(size_t)(cb + lc) * 8192 + rb + lr] = (bf16_t)Tt[lc][lr];
    }
}

// --------------- MHA: reg-cached scores, j halved across thread pairs ------
// Block = 256 threads = one (b,h): thread (t = tid&127, half = tid>>7) does
// 64 j's. Scores kept in 64 VGPRs (no second dot pass); row max shared so
// halves combine by plain addition.
__global__ __launch_bounds__(256, 3)
void k_mha(const bf16_t* __restrict__ qkv, bf16_t* __restrict__ attn) {
    __shared__ float Kl[128][17];
    __shared__ float Vl[128][17];
    __shared__ float mx2[2][128];
    __shared__ float sm1[128];
    __shared__ float ol[128][17];
    const int bh = blockIdx.x;
    const int b = bh >> 4, h = bh & 15;
    const int tid  = threadIdx.x;
    const int t    = tid & 127;
    const int half = tid >> 7;
    const size_t rowbase = (size_t)b * 128;
    const bf16_t* rowp = qkv + (rowbase + t) * 768 + h * 16;

    {   // half0 stages K row t, half1 stages V row t
        const bf16_t* src = rowp + 256 + half * 256;
        bf16x8 a = *(const bf16x8*)(src);
        bf16x8 c = *(const bf16x8*)(src + 8);
        float* dst = half ? &Vl[t][0] : &Kl[t][0];
#pragma unroll
        for (int e = 0; e < 8; ++e) { dst[e] = (float)a[e]; dst[8 + e] = (float)c[e]; }
    }
    float q[16];
    {
        bf16x8 qa = *(const bf16x8*)(rowp);
        bf16x8 qb = *(const bf16x8*)(rowp + 8);
#pragma unroll
        for (int e = 0; e < 8; ++e) { q[e] = (float)qa[e]; q[8 + e] = (float)qb[e]; }
    }
    __syncthreads();

    const int j0 = half * 64;
    float s[64];
    float mx = -1e30f;
#pragma unroll
    for (int j = 0; j < 64; ++j) {
        float v = 0.f;
#pragma unroll
        for (int d = 0; d < 16; ++d) v += q[d] * Kl[j0 + j][d];
        v *= 0.25f;
        s[j] = v;
        mx = fmaxf(mx, v);
    }
    mx2[half][t] = mx;
    __syncthreads();
    const float m = fmaxf(mx2[0][t], mx2[1][t]);

    float sum = 0.f;
    float o[16];
#pragma unroll
    for (int d = 0; d < 16; ++d) o[d] = 0.f;
#pragma unroll
    for (int j = 0; j < 64; ++j) {
        float e = __expf(s[j] - m);
        sum += e;
#pragma unroll
        for (int d = 0; d < 16; ++d) o[d] += e * Vl[j0 + j][d];
    }
    if (half) {
        sm1[t] = sum;
#pragma unroll
        for (int d = 0; d < 16; ++d) ol[t][d] = o[d];
    }
    __syncthreads();
    if (!half) {
        float inv = 1.f / (sum + sm1[t]);
        bf16_t* outp = attn + (rowbase + t) * 256 + h * 16;
#pragma unroll
        for (int d = 0; d < 16; ++d) outp[d] = (bf16_t)((o[d] + ol[t][d]) * inv);
    }
}

// ------------------- k_rowabs: r_i = sum_j |u_i . s_j| (hot) ---------------
// BQ=128, BK=64, j-split x4 (grid 128x4 = 512 blocks -> 2 blocks/CU).
// 8 waves = 2(wr: 64-q strip) x 4(wc: 16-j strip). U register-resident;
// K-tile double-buffered via global_load_lds DMA. ONE barrier per iter;
// co-resident block hides the drain stall.
__global__ __launch_bounds__(512, 4)
void k_rowabs(const bf16_t* __restrict__ Ub, const bf16_t* __restrict__ Sq,
              float* __restrict__ rsp) {
    __shared__ bf16_t Kl[2][64 * 256];   // 2 x 32 KB

    const int tid  = threadIdx.x;
    const int lane = tid & 63;
    const int wid  = tid >> 6;     // 0..7
    const int wr   = wid >> 2;     // 0..1 : 64-row q strip
    const int wc   = wid & 3;      // 0..3 : 16-col j strip
    const int l15  = lane & 15;
    const int l4   = lane >> 4;
    const int q0   = blockIdx.x * 128;
    const int jy   = blockIdx.y;   // 0..3
    const int jbase = jy * 2048;

    // DMA source offsets: dest chunk c -> pre-swizzled source chunk
    int koff[4];
#pragma unroll
    for (int i = 0; i < 4; ++i) {
        int c = wid * 256 + i * 64 + lane;
        int sc = (c & ~31) | ((c & 31) ^ ((c >> 5) & 7));
        koff[i] = sc * 16;
    }
    auto stage = [&](int b, int j0) {
        const char* gK = (const char*)Sq + (size_t)j0 * 512;
        char* lK = (char*)(&Kl[b][0]) + wid * 4096;
#pragma unroll
        for (int i = 0; i < 4; ++i) GLOAD_LDS16(gK + koff[i], lK + i * 1024);
    };

    // U fragments: rows q0 + 64*wr + 16*rt + l15
    bf16x8 uf[4][8];
#pragma unroll
    for (int rt = 0; rt < 4; ++rt) {
        const bf16_t* up = Ub + (size_t)(q0 + 64 * wr + 16 * rt + l15) * 256 + l4 * 8;
#pragma unroll
        for (int t = 0; t < 8; ++t) uf[rt][t] = *(const bf16x8*)(up + t * 32);
    }

    float rsacc[4][4];
#pragma unroll
    for (int rt = 0; rt < 4; ++rt)
#pragma unroll
        for (int r = 0; r < 4; ++r) rsacc[rt][r] = 0.f;

    stage(0, jbase);
    __syncthreads();

    for (int it = 0; it < 32; ++it) {
        const int cur = it & 1;
        if (it + 1 < 32) stage(cur ^ 1, jbase + (it + 1) * 64);
        const bf16_t* Klc = &Kl[cur][0];

        f32x4 sacc[4];
#pragma unroll
        for (int rt = 0; rt < 4; ++rt) sacc[rt] = (f32x4){0.f, 0.f, 0.f, 0.f};
#pragma unroll
        for (int t = 0; t < 8; ++t) {
            int k = t * 32 + l4 * 8;
            bf16x8 bfr = *(const bf16x8*)(Klc + swz256(16 * wc + l15, k));
#pragma unroll
            for (int rt = 0; rt < 4; ++rt)
                sacc[rt] = MFMA16(uf[rt][t], bfr, sacc[rt]);
        }
#pragma unroll
        for (int rt = 0; rt < 4; ++rt)
#pragma unroll
            for (int r = 0; r < 4; ++r) rsacc[rt][r] += fabsf(sacc[rt][r]);
        __syncthreads();   // reads of cur done; DMA to cur^1 drained (vmcnt0)
    }

    // reduce over j within strip (16 lanes), write per-(jy,wc) partial
    float* rdst = rsp + (size_t)(jy * 4 + wc) * 16384 + q0 + 64 * wr;
#pragma unroll
    for (int rt = 0; rt < 4; ++rt)
#pragma unroll
        for (int r = 0; r < 4; ++r) {
            float v = rsacc[rt][r];
            v += __shfl_xor(v, 1, 16);
            v += __shfl_xor(v, 2, 16);
            v += __shfl_xor(v, 4, 16);
            v += __shfl_xor(v, 8, 16);
            if (l15 == 0) rdst[16 * rt + 4 * l4 + r] = v;
        }
}

// ---- Gpart[kz] = ST[rb:, 1024-slice] @ STᵀ (64x64 tile, f32) --------------
__global__ __launch_bounds__(256, 1)
void k_gram(const bf16_t* __restrict__ ST, float* __restrict__ Gpart) {
    __shared__ bf16_t Al[64 * 256];
    __shared__ bf16_t Bl[64 * 256];
    const int tid = threadIdx.x, lane = tid & 63, w = tid >> 6;
    const int l15 = lane & 15, l4 = lane >> 4;
    const int rb = blockIdx.y * 64, cb = blockIdx.x * 64;
    const int jb = blockIdx.z * 1024;

    f32x4 acc[4];
#pragma unroll
    for (int n = 0; n < 4; ++n) acc[n] = (f32x4){0.f, 0.f, 0.f, 0.f};

    for (int kt4 = 0; kt4 < 4; ++kt4) {
        int j0 = jb + kt4 * 256;
        __syncthreads();
        u32x4* da = (u32x4*)Al;
        u32x4* db = (u32x4*)Bl;
#pragma unroll
        for (int i = 0; i < 8; ++i) {
            int ch  = i * 256 + tid;
            int row = ch >> 5, cp = ch & 31;
            int sch = (ch & ~31) | (cp ^ (row & 7));
            da[sch] = *(const u32x4*)(ST + (size_t)(rb + row) * 8192 + j0 + cp * 8);
            db[sch] = *(const u32x4*)(ST + (size_t)(cb + row) * 8192 + j0 + cp * 8);
        }
        __syncthreads();
#pragma unroll
        for (int t = 0; t < 8; ++t) {
            int k = t * 32 + l4 * 8;
            bf16x8 af = *(const bf16x8*)(Al + swz256(16 * w + l15, k));
#pragma unroll
            for (int n = 0; n < 4; ++n) {
                bf16x8 bfr = *(const bf16x8*)(Bl + swz256(16 * n + l15, k));
                acc[n] = MFMA16(af, bfr, acc[n]);
            }
        }
    }
    float* gp = Gpart + (size_t)blockIdx.z * 65536;
#pragma unroll
    for (int n = 0; n < 4; ++n)
#pragma unroll
        for (int r = 0; r < 4; ++r)
            gp[(size_t)(rb + 16 * w + l4 * 4 + r) * 256 + cb + 16 * n + l15] = acc[n][r];
}

// ---- HT = ((sum Gpart) @ trans_wᵀ) transposed, bf16 -----------------------
__global__ __launch_bounds__(256, 1)
void k_gh(const float* __restrict__ Gpart, const float* __restrict__ W,
          bf16_t* __restrict__ HT) {
    __shared__ bf16_t Al[64 * 256];
    __shared__ bf16_t Bl[64 * 256];
    const int tid = threadIdx.x, lane = tid & 63, w = tid >> 6;
    const int l15 = lane & 15, l4 = lane >> 4;
    const int rb = blockIdx.y * 64, cb = blockIdx.x * 64;

#pragma unroll
    for (int i = 0; i < 16; ++i) {
        int idx = i * 1024 + tid * 4;
        int row = idx >> 8, col = idx & 255;
        f32x4 s = *(const f32x4*)(Gpart + (size_t)(rb + row) * 256 + col);
#pragma unroll
        for (int p = 1; p < 8; ++p)
            s += *(const f32x4*)(Gpart + (size_t)p * 65536 + (size_t)(rb + row) * 256 + col);
        f32x4 wv = *(const f32x4*)(W + (size_t)(cb + row) * 256 + col);
        int sc = col ^ ((row & 7) << 3);
        bf16x4 ga = { (bf16_t)s[0], (bf16_t)s[1], (bf16_t)s[2], (bf16_t)s[3] };
        bf16x4 wb = { (bf16_t)wv[0], (bf16_t)wv[1], (bf16_t)wv[2], (bf16_t)wv[3] };
        *(bf16x4*)(Al + row * 256 + sc) = ga;
        *(bf16x4*)(Bl + row * 256 + sc) = wb;
    }
    __syncthreads();

    f32x4 acc[4];
#pragma unroll
    for (int n = 0; n < 4; ++n) acc[n] = (f32x4){0.f, 0.f, 0.f, 0.f};
#pragma unroll
    for (int t = 0; t < 8; ++t) {
        int k = t * 32 + l4 * 8;
        bf16x8 af = *(const bf16x8*)(Al + swz256(16 * w + l15, k));
#pragma unroll
        for (int n = 0; n < 4; ++n) {
            bf16x8 bfr = *(const bf16x8*)(Bl + swz256(16 * n + l15, k));
            acc[n] = MFMA16(af, bfr, acc[n]);
        }
    }
#pragma unroll
    for (int n = 0; n < 4; ++n)
#pragma unroll
        for (int r = 0; r < 4; ++r)
            HT[(size_t)(cb + 16 * n + l15) * 256 + rb + 16 * w + l4 * 4 + r] =
                (bf16_t)acc[n][r];
}

// ---- final: out = user + diag(c) * (U @ HTᵀ) + trans_b; c from rsp --------
__global__ __launch_bounds__(256, 1)
void k_final(const bf16_t* __restrict__ A, const bf16_t* __restrict__ B,
             const float* __restrict__ rsp, const float* __restrict__ tb,
             const float* __restrict__ user, float* __restrict__ out) {
    __shared__ bf16_t Al[64 * 256];
    __shared__ bf16_t Bl[64 * 256];
    __shared__ float  crs[64];
    const int tid  = threadIdx.x;
    const int lane = tid & 63;
    const int w    = tid >> 6;
    const int l15  = lane & 15;
    const int l4   = lane >> 4;
    const int rb = blockIdx.y * 64, cb = blockIdx.x * 64;

    {
        const u32x4* sa = (const u32x4*)(A + (size_t)rb * 256);
        const u32x4* sb = (const u32x4*)(B + (size_t)cb * 256);
        u32x4* da = (u32x4*)Al;
        u32x4* db = (u32x4*)Bl;
#pragma unroll
        for (int i = 0; i < 8; ++i) {
            int ch  = i * 256 + tid;
            int row = ch >> 5, cp = ch & 31;
            int sch = (ch & ~31) | (cp ^ (row & 7));
            da[sch] = sa[ch];
            db[sch] = sb[ch];
        }
    }
    if (tid < 64) {
        float s = 0.f;
#pragma unroll
        for (int p = 0; p < 16; ++p) s += rsp[(size_t)p * 16384 + rb + tid];
        crs[tid] = 1.f / (fmaxf(s, 1e-12f) * 8192.f);
    }
    __syncthreads();

    f32x4 acc[4];
#pragma unroll
    for (int n = 0; n < 4; ++n) acc[n] = (f32x4){0.f, 0.f, 0.f, 0.f};
#pragma unroll
    for (int t = 0; t < 8; ++t) {
        int k = t * 32 + l4 * 8;
        bf16x8 af = *(const bf16x8*)(Al + swz256(16 * w + l15, k));
#pragma unroll
        for (int n = 0; n < 4; ++n) {
            bf16x8 bfr = *(const bf16x8*)(Bl + swz256(16 * n + l15, k));
            acc[n] = MFMA16(af, bfr, acc[n]);
        }
    }
    float c[4];
#pragma unroll
    for (int r = 0; r < 4; ++r) c[r] = crs[16 * w + l4 * 4 + r];
#pragma unroll
    for (int n = 0; n < 4; ++n) {
        int col = cb + 16 * n + l15;
        float bv = tb[col];
#pragma unroll
        for (int r = 0; r < 4; ++r) {
            int row = rb + 16 * w + l4 * 4 + r;
            size_t idx = (size_t)row * 256 + col;
            out[idx] = user[idx] + c[r] * acc[n][r] + bv;
        }
    }
}

// ---------------------------------------------------------------------------
extern "C" void kernel_launch(void* const* d_in, const int* in_sizes, int n_in,
                              void* d_out, int out_size, void* d_ws, size_t ws_size,
                              hipStream_t stream) {
    const float* user_feat  = (const float*)d_in[0];   // [16384,256]
    const float* seq_feat   = (const float*)d_in[1];   // [64,128,256]
    const float* in_proj_w  = (const float*)d_in[2];   // [768,256]
    const float* in_proj_b  = (const float*)d_in[3];   // [768]
    const float* out_proj_w = (const float*)d_in[4];   // [256,256]
    const float* out_proj_b = (const float*)d_in[5];   // [256]
    const float* trans_w    = (const float*)d_in[6];   // [256,256]
    const float* trans_b    = (const float*)d_in[7];   // [256]
    float* out = (float*)d_out;                        // [16384,256]

    char* w = (char*)d_ws;
    size_t off = 0;
    auto take = [&](size_t bytes) { void* p = w + off; off += (bytes + 255) & ~(size_t)255; return p; };
    bf16_t* Ub    = (bf16_t*)take((size_t)16384 * 256 * 2);
    bf16_t* Xb    = (bf16_t*)take((size_t)8192 * 256 * 2);   // dead after qkv -> rsp here
    bf16_t* W1b   = (bf16_t*)take((size_t)768 * 256 * 2);
    bf16_t* W2b   = (bf16_t*)take((size_t)256 * 256 * 2);
    bf16_t* attnb = (bf16_t*)take((size_t)8192 * 256 * 2);
    bf16_t* seqb  = (bf16_t*)take((size_t)8192 * 256 * 2);
    bf16_t* seqTb = (bf16_t*)take((size_t)256 * 8192 * 2);
    char*   regA  = (char*)take((size_t)8192 * 768 * 4);     // 25.17 MB shared region
    bf16_t* qkvb  = (bf16_t*)regA;                           // [8192,768] bf16, dies after MHA
    float*  Gpart = (float*)regA;                            // [8,256,256] f32 = 2 MB
    bf16_t* HTb   = (bf16_t*)(regA + (size_t)8 * 65536 * 4); // [256,256] bf16
    float*  rsp   = (float*)Xb;                              // [16,16384] f32 = 1 MB

    // 1) bf16 casts (one kernel)
    k_cvt_all<<<2048, 256, 0, stream>>>(user_feat, seq_feat, in_proj_w, out_proj_w,
                                        Ub, Xb, W1b, W2b);

    // 2) qkv = seq_feat @ in_proj_wᵀ + in_proj_b   [8192,768] bf16
    k_gemm_bt<<<dim3(12, 128), 256, 0, stream>>>(Xb, W1b, in_proj_b, qkvb, 768);

    // 3) MHA -> attn bf16 [8192,256]
    k_mha<<<1024, 256, 0, stream>>>(qkvb, attnb);

    // 4) seq = attn @ out_proj_wᵀ + out_proj_b -> seqb + seqTb
    k_gemm_seqT<<<dim3(4, 128), 256, 0, stream>>>(attnb, W2b, out_proj_b, seqb, seqTb);

    // 5) rowabs partials (hot; j-split x4 -> 2 blocks/CU)
    k_rowabs<<<dim3(128, 4), 512, 0, stream>>>(Ub, seqb, rsp);

    // 6) G partials, then HT = (G @ trans_wᵀ)ᵀ bf16
    k_gram<<<dim3(4, 4, 8), 256, 0, stream>>>(seqTb, Gpart);
    k_gh<<<dim3(4, 4), 256, 0, stream>>>(Gpart, trans_w, HTb);

    // 7) out = user + diag(c)·(U@H) + trans_b  (c computed from rsp in-block)
    k_final<<<dim3(4, 256), 256, 0, stream>>>(Ub, HTb, rsp, trans_b, user_feat, out);
}

// Round 7
// 169.770 us; speedup vs baseline: 2.2947x; 2.2947x over previous
//
#include <hip/hip_runtime.h>

// ---------------------------------------------------------------------------
// RefineIUGraphLayer: D=256, H=16, HD=16, N=16384, B=64, S=128, M=8192
// Identity: p1-normalize needs |.| only in the DENOMINATOR.
//   out = user + diag(c) · U @ (G Wᵀ) + b,  G = SᵀS,  c_i = 1/(max(r_i,eps)·M)
//   r_i = Σ_j |u_i · s_j|   (the only O(N·M·D) kernel)
// Pipeline (8 launches):
//   1) cvt_all: user/seq_feat/in_proj_w/out_proj_w -> bf16
//   2) qkv  = seq_feat @ in_proj_wᵀ + b        (bf16 MFMA gemm)
//   3) attn = MHA(qkv)                         (reg-cached scores, 2 j-halves)
//   4) seq  = attn @ out_proj_wᵀ + b           (gemm, writes seq + seqᵀ)
//   5) r    = rowabs(U @ seqᵀ)                 (hot; j-split x4, 2 blocks/CU)
//   6) G    = seqᵀ seq (split-K partials)
//   7) Hᵀ   = (ΣGpart) @ trans_wᵀ  (bf16, transposed)
//   8) out  = user + diag(c)·(U@H) + trans_b   (c computed in-block)
// NOTE (R6 lesson): k_rowabs MUST keep __launch_bounds__(512,2) — a tighter
// VGPR cap (512,4 -> 64 VGPR) evicts the 128-VGPR U-fragment array to global
// re-loads (FETCH 1 GB, 4x slowdown). 96 VGPR rounds to the 128 bucket ->
// 4 waves/EU -> 2 blocks/CU anyway.
// ---------------------------------------------------------------------------

typedef __bf16 bf16_t;
typedef __bf16 bf16x8 __attribute__((ext_vector_type(8)));
typedef __bf16 bf16x4 __attribute__((ext_vector_type(4)));
typedef float  f32x4  __attribute__((ext_vector_type(4)));
typedef unsigned int u32x4 __attribute__((ext_vector_type(4)));

#define MFMA16(a, b, c) __builtin_amdgcn_mfma_f32_16x16x32_bf16((a), (b), (c), 0, 0, 0)

#define AS1 __attribute__((address_space(1)))
#define AS3 __attribute__((address_space(3)))
#define GLOAD_LDS16(g, l) \
    __builtin_amdgcn_global_load_lds((const AS1 unsigned int*)(const void*)(g), \
                                     (AS3 unsigned int*)(void*)(l), 16, 0, 0)

// 3-bit chunk XOR swizzle (involution; same on write & read).
__device__ __forceinline__ int swz256(int row, int k) { return row * 256 + (k ^ ((row & 7) << 3)); }

// ------------------ fused f32 -> bf16 convert (all operands) ---------------
__global__ void k_cvt_all(const float* __restrict__ u, const float* __restrict__ x,
                          const float* __restrict__ w1, const float* __restrict__ w2,
                          bf16_t* __restrict__ ub, bf16_t* __restrict__ xb,
                          bf16_t* __restrict__ w1b, bf16_t* __restrict__ w2b) {
    const int NU = 16384 * 256 / 4, NX = 8192 * 256 / 4;
    const int NW1 = 768 * 256 / 4, NW2 = 256 * 256 / 4;
    const int total = NU + NX + NW1 + NW2;
    int i  = blockIdx.x * blockDim.x + threadIdx.x;
    int st = gridDim.x * blockDim.x;
    for (; i < total; i += st) {
        const float* s; bf16_t* d; int k;
        if (i < NU)                { s = u;  d = ub;  k = i; }
        else if (i < NU + NX)      { s = x;  d = xb;  k = i - NU; }
        else if (i < NU + NX + NW1){ s = w1; d = w1b; k = i - NU - NX; }
        else                       { s = w2; d = w2b; k = i - NU - NX - NW1; }
        float4 v = ((const float4*)s)[k];
        bf16x4 o = { (bf16_t)v.x, (bf16_t)v.y, (bf16_t)v.z, (bf16_t)v.w };
        ((bf16x4*)d)[k] = o;
    }
}

// --------------- generic C = A @ Bᵀ + bias, bf16 out -----------------------
__global__ __launch_bounds__(256, 1)
void k_gemm_bt(const bf16_t* __restrict__ A, const bf16_t* __restrict__ B,
               const float* __restrict__ bias, bf16_t* __restrict__ Cb, int N) {
    __shared__ bf16_t Al[64 * 256];
    __shared__ bf16_t Bl[64 * 256];
    const int tid  = threadIdx.x;
    const int lane = tid & 63;
    const int w    = tid >> 6;
    const int l15  = lane & 15;
    const int l4   = lane >> 4;
    const int rb = blockIdx.y * 64, cb = blockIdx.x * 64;

    {
        const u32x4* sa = (const u32x4*)(A + (size_t)rb * 256);
        const u32x4* sb = (const u32x4*)(B + (size_t)cb * 256);
        u32x4* da = (u32x4*)Al;
        u32x4* db = (u32x4*)Bl;
#pragma unroll
        for (int i = 0; i < 8; ++i) {
            int ch  = i * 256 + tid;
            int row = ch >> 5, cp = ch & 31;
            int sch = (ch & ~31) | (cp ^ (row & 7));
            da[sch] = sa[ch];
            db[sch] = sb[ch];
        }
    }
    __syncthreads();

    f32x4 acc[4];
#pragma unroll
    for (int n = 0; n < 4; ++n) acc[n] = (f32x4){0.f, 0.f, 0.f, 0.f};
#pragma unroll
    for (int t = 0; t < 8; ++t) {
        int k = t * 32 + l4 * 8;
        bf16x8 af = *(const bf16x8*)(Al + swz256(16 * w + l15, k));
#pragma unroll
        for (int n = 0; n < 4; ++n) {
            bf16x8 bfr = *(const bf16x8*)(Bl + swz256(16 * n + l15, k));
            acc[n] = MFMA16(af, bfr, acc[n]);
        }
    }
#pragma unroll
    for (int n = 0; n < 4; ++n) {
        int col = cb + 16 * n + l15;
        float bv = bias ? bias[col] : 0.f;
#pragma unroll
        for (int r = 0; r < 4; ++r) {
            int row = rb + 16 * w + l4 * 4 + r;
            Cb[(size_t)row * N + col] = (bf16_t)(acc[n][r] + bv);
        }
    }
}

// -------- seq gemm: C = A @ Bᵀ + bias; writes C (bf16) AND Cᵀ (bf16) -------
__global__ __launch_bounds__(256, 1)
void k_gemm_seqT(const bf16_t* __restrict__ A, const bf16_t* __restrict__ B,
                 const float* __restrict__ bias, bf16_t* __restrict__ Cb,
                 bf16_t* __restrict__ CTb) {
    __shared__ bf16_t Al[64 * 256];
    __shared__ bf16_t Bl[64 * 256];
    __shared__ float  Tt[64][65];
    const int tid  = threadIdx.x;
    const int lane = tid & 63;
    const int w    = tid >> 6;
    const int l15  = lane & 15;
    const int l4   = lane >> 4;
    const int rb = blockIdx.y * 64, cb = blockIdx.x * 64;

    {
        const u32x4* sa = (const u32x4*)(A + (size_t)rb * 256);
        const u32x4* sb = (const u32x4*)(B + (size_t)cb * 256);
        u32x4* da = (u32x4*)Al;
        u32x4* db = (u32x4*)Bl;
#pragma unroll
        for (int i = 0; i < 8; ++i) {
            int ch  = i * 256 + tid;
            int row = ch >> 5, cp = ch & 31;
            int sch = (ch & ~31) | (cp ^ (row & 7));
            da[sch] = sa[ch];
            db[sch] = sb[ch];
        }
    }
    __syncthreads();

    f32x4 acc[4];
#pragma unroll
    for (int n = 0; n < 4; ++n) acc[n] = (f32x4){0.f, 0.f, 0.f, 0.f};
#pragma unroll
    for (int t = 0; t < 8; ++t) {
        int k = t * 32 + l4 * 8;
        bf16x8 af = *(const bf16x8*)(Al + swz256(16 * w + l15, k));
#pragma unroll
        for (int n = 0; n < 4; ++n) {
            bf16x8 bfr = *(const bf16x8*)(Bl + swz256(16 * n + l15, k));
            acc[n] = MFMA16(af, bfr, acc[n]);
        }
    }
#pragma unroll
    for (int n = 0; n < 4; ++n) {
        int col = cb + 16 * n + l15;
        float bv = bias[col];
#pragma unroll
        for (int r = 0; r < 4; ++r) {
            int row = rb + 16 * w + l4 * 4 + r;
            float v = acc[n][r] + bv;
            Cb[(size_t)row * 256 + col] = (bf16_t)v;
            Tt[16 * n + l15][16 * w + l4 * 4 + r] = v;
        }
    }
    __syncthreads();
#pragma unroll
    for (int i = 0; i < 16; ++i) {
        int e = i * 256 + tid;
        int lc = e >> 6, lr = e & 63;
        CTb[(size_t)(cb + lc) * 8192 + rb + lr] = (bf16_t)Tt[lc][lr];
    }
}

// --------------- MHA: reg-cached scores, j halved across thread pairs ------
__global__ __launch_bounds__(256, 3)
void k_mha(const bf16_t* __restrict__ qkv, bf16_t* __restrict__ attn) {
    __shared__ float Kl[128][17];
    __shared__ float Vl[128][17];
    __shared__ float mx2[2][128];
    __shared__ float sm1[128];
    __shared__ float ol[128][17];
    const int bh = blockIdx.x;
    const int b = bh >> 4, h = bh & 15;
    const int tid  = threadIdx.x;
    const int t    = tid & 127;
    const int half = tid >> 7;
    const size_t rowbase = (size_t)b * 128;
    const bf16_t* rowp = qkv + (rowbase + t) * 768 + h * 16;

    {   // half0 stages K row t, half1 stages V row t
        const bf16_t* src = rowp + 256 + half * 256;
        bf16x8 a = *(const bf16x8*)(src);
        bf16x8 c = *(const bf16x8*)(src + 8);
        float* dst = half ? &Vl[t][0] : &Kl[t][0];
#pragma unroll
        for (int e = 0; e < 8; ++e) { dst[e] = (float)a[e]; dst[8 + e] = (float)c[e]; }
    }
    float q[16];
    {
        bf16x8 qa = *(const bf16x8*)(rowp);
        bf16x8 qb = *(const bf16x8*)(rowp + 8);
#pragma unroll
        for (int e = 0; e < 8; ++e) { q[e] = (float)qa[e]; q[8 + e] = (float)qb[e]; }
    }
    __syncthreads();

    const int j0 = half * 64;
    float s[64];
    float mx = -1e30f;
#pragma unroll
    for (int j = 0; j < 64; ++j) {
        float v = 0.f;
#pragma unroll
        for (int d = 0; d < 16; ++d) v += q[d] * Kl[j0 + j][d];
        v *= 0.25f;
        s[j] = v;
        mx = fmaxf(mx, v);
    }
    mx2[half][t] = mx;
    __syncthreads();
    const float m = fmaxf(mx2[0][t], mx2[1][t]);

    float sum = 0.f;
    float o[16];
#pragma unroll
    for (int d = 0; d < 16; ++d) o[d] = 0.f;
#pragma unroll
    for (int j = 0; j < 64; ++j) {
        float e = __expf(s[j] - m);
        sum += e;
#pragma unroll
        for (int d = 0; d < 16; ++d) o[d] += e * Vl[j0 + j][d];
    }
    if (half) {
        sm1[t] = sum;
#pragma unroll
        for (int d = 0; d < 16; ++d) ol[t][d] = o[d];
    }
    __syncthreads();
    if (!half) {
        float inv = 1.f / (sum + sm1[t]);
        bf16_t* outp = attn + (rowbase + t) * 256 + h * 16;
#pragma unroll
        for (int d = 0; d < 16; ++d) outp[d] = (bf16_t)((o[d] + ol[t][d]) * inv);
    }
}

// ------------------- k_rowabs: r_i = sum_j |u_i . s_j| (hot) ---------------
// BQ=128, BK=64, j-split x4 (grid 128x4 = 512 blocks). 8 waves =
// 2(wr) x 4(wc). U register-resident (128 VGPR -> total ~96-128; DO NOT
// tighten launch_bounds, see header note). K-tile double-buffered via
// global_load_lds DMA. ONE barrier per iter; with ~96 VGPR the HW fits
// 2 blocks/CU and the co-resident block hides the drain stall.
__global__ __launch_bounds__(512, 2)
void k_rowabs(const bf16_t* __restrict__ Ub, const bf16_t* __restrict__ Sq,
              float* __restrict__ rsp) {
    __shared__ bf16_t Kl[2][64 * 256];   // 2 x 32 KB

    const int tid  = threadIdx.x;
    const int lane = tid & 63;
    const int wid  = tid >> 6;     // 0..7
    const int wr   = wid >> 2;     // 0..1 : 64-row q strip
    const int wc   = wid & 3;      // 0..3 : 16-col j strip
    const int l15  = lane & 15;
    const int l4   = lane >> 4;
    const int q0   = blockIdx.x * 128;
    const int jy   = blockIdx.y;   // 0..3
    const int jbase = jy * 2048;

    // DMA source offsets: dest chunk c -> pre-swizzled source chunk
    int koff[4];
#pragma unroll
    for (int i = 0; i < 4; ++i) {
        int c = wid * 256 + i * 64 + lane;
        int sc = (c & ~31) | ((c & 31) ^ ((c >> 5) & 7));
        koff[i] = sc * 16;
    }
    auto stage = [&](int b, int j0) {
        const char* gK = (const char*)Sq + (size_t)j0 * 512;
        char* lK = (char*)(&Kl[b][0]) + wid * 4096;
#pragma unroll
        for (int i = 0; i < 4; ++i) GLOAD_LDS16(gK + koff[i], lK + i * 1024);
    };

    // U fragments: rows q0 + 64*wr + 16*rt + l15
    bf16x8 uf[4][8];
#pragma unroll
    for (int rt = 0; rt < 4; ++rt) {
        const bf16_t* up = Ub + (size_t)(q0 + 64 * wr + 16 * rt + l15) * 256 + l4 * 8;
#pragma unroll
        for (int t = 0; t < 8; ++t) uf[rt][t] = *(const bf16x8*)(up + t * 32);
    }

    float rsacc[4][4];
#pragma unroll
    for (int rt = 0; rt < 4; ++rt)
#pragma unroll
        for (int r = 0; r < 4; ++r) rsacc[rt][r] = 0.f;

    stage(0, jbase);
    __syncthreads();

    for (int it = 0; it < 32; ++it) {
        const int cur = it & 1;
        if (it + 1 < 32) stage(cur ^ 1, jbase + (it + 1) * 64);
        const bf16_t* Klc = &Kl[cur][0];

        f32x4 sacc[4];
#pragma unroll
        for (int rt = 0; rt < 4; ++rt) sacc[rt] = (f32x4){0.f, 0.f, 0.f, 0.f};
#pragma unroll
        for (int t = 0; t < 8; ++t) {
            int k = t * 32 + l4 * 8;
            bf16x8 bfr = *(const bf16x8*)(Klc + swz256(16 * wc + l15, k));
#pragma unroll
            for (int rt = 0; rt < 4; ++rt)
                sacc[rt] = MFMA16(uf[rt][t], bfr, sacc[rt]);
        }
#pragma unroll
        for (int rt = 0; rt < 4; ++rt)
#pragma unroll
            for (int r = 0; r < 4; ++r) rsacc[rt][r] += fabsf(sacc[rt][r]);
        __syncthreads();   // reads of cur done; DMA to cur^1 drained (vmcnt0)
    }

    // reduce over j within strip (16 lanes), write per-(jy,wc) partial
    float* rdst = rsp + (size_t)(jy * 4 + wc) * 16384 + q0 + 64 * wr;
#pragma unroll
    for (int rt = 0; rt < 4; ++rt)
#pragma unroll
        for (int r = 0; r < 4; ++r) {
            float v = rsacc[rt][r];
            v += __shfl_xor(v, 1, 16);
            v += __shfl_xor(v, 2, 16);
            v += __shfl_xor(v, 4, 16);
            v += __shfl_xor(v, 8, 16);
            if (l15 == 0) rdst[16 * rt + 4 * l4 + r] = v;
        }
}

// ---- Gpart[kz] = ST[rb:, 1024-slice] @ STᵀ (64x64 tile, f32) --------------
__global__ __launch_bounds__(256, 1)
void k_gram(const bf16_t* __restrict__ ST, float* __restrict__ Gpart) {
    __shared__ bf16_t Al[64 * 256];
    __shared__ bf16_t Bl[64 * 256];
    const int tid = threadIdx.x, lane = tid & 63, w = tid >> 6;
    const int l15 = lane & 15, l4 = lane >> 4;
    const int rb = blockIdx.y * 64, cb = blockIdx.x * 64;
    const int jb = blockIdx.z * 1024;

    f32x4 acc[4];
#pragma unroll
    for (int n = 0; n < 4; ++n) acc[n] = (f32x4){0.f, 0.f, 0.f, 0.f};

    for (int kt4 = 0; kt4 < 4; ++kt4) {
        int j0 = jb + kt4 * 256;
        __syncthreads();
        u32x4* da = (u32x4*)Al;
        u32x4* db = (u32x4*)Bl;
#pragma unroll
        for (int i = 0; i < 8; ++i) {
            int ch  = i * 256 + tid;
            int row = ch >> 5, cp = ch & 31;
            int sch = (ch & ~31) | (cp ^ (row & 7));
            da[sch] = *(const u32x4*)(ST + (size_t)(rb + row) * 8192 + j0 + cp * 8);
            db[sch] = *(const u32x4*)(ST + (size_t)(cb + row) * 8192 + j0 + cp * 8);
        }
        __syncthreads();
#pragma unroll
        for (int t = 0; t < 8; ++t) {
            int k = t * 32 + l4 * 8;
            bf16x8 af = *(const bf16x8*)(Al + swz256(16 * w + l15, k));
#pragma unroll
            for (int n = 0; n < 4; ++n) {
                bf16x8 bfr = *(const bf16x8*)(Bl + swz256(16 * n + l15, k));
                acc[n] = MFMA16(af, bfr, acc[n]);
            }
        }
    }
    float* gp = Gpart + (size_t)blockIdx.z * 65536;
#pragma unroll
    for (int n = 0; n < 4; ++n)
#pragma unroll
        for (int r = 0; r < 4; ++r)
            gp[(size_t)(rb + 16 * w + l4 * 4 + r) * 256 + cb + 16 * n + l15] = acc[n][r];
}

// ---- HT = ((sum Gpart) @ trans_wᵀ) transposed, bf16 -----------------------
__global__ __launch_bounds__(256, 1)
void k_gh(const float* __restrict__ Gpart, const float* __restrict__ W,
          bf16_t* __restrict__ HT) {
    __shared__ bf16_t Al[64 * 256];
    __shared__ bf16_t Bl[64 * 256];
    const int tid = threadIdx.x, lane = tid & 63, w = tid >> 6;
    const int l15 = lane & 15, l4 = lane >> 4;
    const int rb = blockIdx.y * 64, cb = blockIdx.x * 64;

#pragma unroll
    for (int i = 0; i < 16; ++i) {
        int idx = i * 1024 + tid * 4;
        int row = idx >> 8, col = idx & 255;
        f32x4 s = *(const f32x4*)(Gpart + (size_t)(rb + row) * 256 + col);
#pragma unroll
        for (int p = 1; p < 8; ++p)
            s += *(const f32x4*)(Gpart + (size_t)p * 65536 + (size_t)(rb + row) * 256 + col);
        f32x4 wv = *(const f32x4*)(W + (size_t)(cb + row) * 256 + col);
        int sc = col ^ ((row & 7) << 3);
        bf16x4 ga = { (bf16_t)s[0], (bf16_t)s[1], (bf16_t)s[2], (bf16_t)s[3] };
        bf16x4 wb = { (bf16_t)wv[0], (bf16_t)wv[1], (bf16_t)wv[2], (bf16_t)wv[3] };
        *(bf16x4*)(Al + row * 256 + sc) = ga;
        *(bf16x4*)(Bl + row * 256 + sc) = wb;
    }
    __syncthreads();

    f32x4 acc[4];
#pragma unroll
    for (int n = 0; n < 4; ++n) acc[n] = (f32x4){0.f, 0.f, 0.f, 0.f};
#pragma unroll
    for (int t = 0; t < 8; ++t) {
        int k = t * 32 + l4 * 8;
        bf16x8 af = *(const bf16x8*)(Al + swz256(16 * w + l15, k));
#pragma unroll
        for (int n = 0; n < 4; ++n) {
            bf16x8 bfr = *(const bf16x8*)(Bl + swz256(16 * n + l15, k));
            acc[n] = MFMA16(af, bfr, acc[n]);
        }
    }
#pragma unroll
    for (int n = 0; n < 4; ++n)
#pragma unroll
        for (int r = 0; r < 4; ++r)
            HT[(size_t)(cb + 16 * n + l15) * 256 + rb + 16 * w + l4 * 4 + r] =
                (bf16_t)acc[n][r];
}

// ---- final: out = user + diag(c) * (U @ HTᵀ) + trans_b; c from rsp --------
__global__ __launch_bounds__(256, 1)
void k_final(const bf16_t* __restrict__ A, const bf16_t* __restrict__ B,
             const float* __restrict__ rsp, const float* __restrict__ tb,
             const float* __restrict__ user, float* __restrict__ out) {
    __shared__ bf16_t Al[64 * 256];
    __shared__ bf16_t Bl[64 * 256];
    __shared__ float  crs[64];
    const int tid  = threadIdx.x;
    const int lane = tid & 63;
    const int w    = tid >> 6;
    const int l15  = lane & 15;
    const int l4   = lane >> 4;
    const int rb = blockIdx.y * 64, cb = blockIdx.x * 64;

    {
        const u32x4* sa = (const u32x4*)(A + (size_t)rb * 256);
        const u32x4* sb = (const u32x4*)(B + (size_t)cb * 256);
        u32x4* da = (u32x4*)Al;
        u32x4* db = (u32x4*)Bl;
#pragma unroll
        for (int i = 0; i < 8; ++i) {
            int ch  = i * 256 + tid;
            int row = ch >> 5, cp = ch & 31;
            int sch = (ch & ~31) | (cp ^ (row & 7));
            da[sch] = sa[ch];
            db[sch] = sb[ch];
        }
    }
    if (tid < 64) {
        float s = 0.f;
#pragma unroll
        for (int p = 0; p < 16; ++p) s += rsp[(size_t)p * 16384 + rb + tid];
        crs[tid] = 1.f / (fmaxf(s, 1e-12f) * 8192.f);
    }
    __syncthreads();

    f32x4 acc[4];
#pragma unroll
    for (int n = 0; n < 4; ++n) acc[n] = (f32x4){0.f, 0.f, 0.f, 0.f};
#pragma unroll
    for (int t = 0; t < 8; ++t) {
        int k = t * 32 + l4 * 8;
        bf16x8 af = *(const bf16x8*)(Al + swz256(16 * w + l15, k));
#pragma unroll
        for (int n = 0; n < 4; ++n) {
            bf16x8 bfr = *(const bf16x8*)(Bl + swz256(16 * n + l15, k));
            acc[n] = MFMA16(af, bfr, acc[n]);
        }
    }
    float c[4];
#pragma unroll
    for (int r = 0; r < 4; ++r) c[r] = crs[16 * w + l4 * 4 + r];
#pragma unroll
    for (int n = 0; n < 4; ++n) {
        int col = cb + 16 * n + l15;
        float bv = tb[col];
#pragma unroll
        for (int r = 0; r < 4; ++r) {
            int row = rb + 16 * w + l4 * 4 + r;
            size_t idx = (size_t)row * 256 + col;
            out[idx] = user[idx] + c[r] * acc[n][r] + bv;
        }
    }
}

// ---------------------------------------------------------------------------
extern "C" void kernel_launch(void* const* d_in, const int* in_sizes, int n_in,
                              void* d_out, int out_size, void* d_ws, size_t ws_size,
                              hipStream_t stream) {
    const float* user_feat  = (const float*)d_in[0];   // [16384,256]
    const float* seq_feat   = (const float*)d_in[1];   // [64,128,256]
    const float* in_proj_w  = (const float*)d_in[2];   // [768,256]
    const float* in_proj_b  = (const float*)d_in[3];   // [768]
    const float* out_proj_w = (const float*)d_in[4];   // [256,256]
    const float* out_proj_b = (const float*)d_in[5];   // [256]
    const float* trans_w    = (const float*)d_in[6];   // [256,256]
    const float* trans_b    = (const float*)d_in[7];   // [256]
    float* out = (float*)d_out;                        // [16384,256]

    char* w = (char*)d_ws;
    size_t off = 0;
    auto take = [&](size_t bytes) { void* p = w + off; off += (bytes + 255) & ~(size_t)255; return p; };
    bf16_t* Ub    = (bf16_t*)take((size_t)16384 * 256 * 2);
    bf16_t* Xb    = (bf16_t*)take((size_t)8192 * 256 * 2);   // dead after qkv -> rsp here
    bf16_t* W1b   = (bf16_t*)take((size_t)768 * 256 * 2);
    bf16_t* W2b   = (bf16_t*)take((size_t)256 * 256 * 2);
    bf16_t* attnb = (bf16_t*)take((size_t)8192 * 256 * 2);
    bf16_t* seqb  = (bf16_t*)take((size_t)8192 * 256 * 2);
    bf16_t* seqTb = (bf16_t*)take((size_t)256 * 8192 * 2);
    char*   regA  = (char*)take((size_t)8192 * 768 * 4);     // 25.17 MB shared region
    bf16_t* qkvb  = (bf16_t*)regA;                           // [8192,768] bf16, dies after MHA
    float*  Gpart = (float*)regA;                            // [8,256,256] f32 = 2 MB
    bf16_t* HTb   = (bf16_t*)(regA + (size_t)8 * 65536 * 4); // [256,256] bf16
    float*  rsp   = (float*)Xb;                              // [16,16384] f32 = 1 MB

    // 1) bf16 casts (one kernel)
    k_cvt_all<<<2048, 256, 0, stream>>>(user_feat, seq_feat, in_proj_w, out_proj_w,
                                        Ub, Xb, W1b, W2b);

    // 2) qkv = seq_feat @ in_proj_wᵀ + in_proj_b   [8192,768] bf16
    k_gemm_bt<<<dim3(12, 128), 256, 0, stream>>>(Xb, W1b, in_proj_b, qkvb, 768);

    // 3) MHA -> attn bf16 [8192,256]
    k_mha<<<1024, 256, 0, stream>>>(qkvb, attnb);

    // 4) seq = attn @ out_proj_wᵀ + out_proj_b -> seqb + seqTb
    k_gemm_seqT<<<dim3(4, 128), 256, 0, stream>>>(attnb, W2b, out_proj_b, seqb, seqTb);

    // 5) rowabs partials (hot; j-split x4, natural VGPR -> 2 blocks/CU)
    k_rowabs<<<dim3(128, 4), 512, 0, stream>>>(Ub, seqb, rsp);

    // 6) G partials, then HT = (G @ trans_wᵀ)ᵀ bf16
    k_gram<<<dim3(4, 4, 8), 256, 0, stream>>>(seqTb, Gpart);
    k_gh<<<dim3(4, 4), 256, 0, stream>>>(Gpart, trans_w, HTb);

    // 7) out = user + diag(c)·(U@H) + trans_b  (c computed from rsp in-block)
    k_final<<<dim3(4, 256), 256, 0, stream>>>(Ub, HTb, rsp, trans_b, user_feat, out);
}